// Round 11
// baseline (302.957 us; speedup 1.0000x reference)
//
#include <hip/hip_runtime.h>

#define RR 4
#define NS 17
#define BB 4
#define CC 128
#define HH 96
#define WW 160
#define HWSZ (HH * WW)

// TH=2 vertical-reuse on the r1-proven skeleton. Each thread owns TWO
// vertically-adjacent pixels; one 10-read center column serves both pixels'
// up/center/down shifts (26 ds_read_b128 per 2 px vs 34), and the 16x32
// pixel tile improves halo ratio (1.875 staged f4/px vs 2.5).
// Skeleton literal: store-early, 2 barriers/phase, depth-1 prefetch, CG=4.
//
// SESSION LAWS (counter-proven):
//  - ATOMIC LAW: <=4 writers/output, all on ONE XCD (chunk flat-stride
//    120 == 0 mod 8 here). 8 writers or XCD-spanning writers -> 15-40x
//    write inflation (r5/r6/r8).
//  - VGPR LAW: never bound below live set (r7). (256,4) cap=128; live
//    ~100 here. Tripwire: symmetric fetch/write inflation = spill.
//  - r1 skeleton only: write-late (r2/r3) and depth-2 A/B (r8) dirty.
//  - r10 null: waves/CU 15->30 was neutral -> occupancy NOT binding;
//    this round tests 7.5 waves/CU (if latency-bound: revert to r10).
// TRIPWIRES: WRITE_SIZE ~16.3 MB; VGPR <=128; FETCH 55-65 MB.
#define TW 32
#define HTILE 16                 // block pixel rows (TH=2 per thread)
#define TH 2
#define TROWS (HTILE + 2 * RR)   // 24
#define TCOLS (TW + 2 * RR)      // 40
#define TILE_E (TROWS * TCOLS)   // 960 float4 = 15360 B
#define CCHUNK 32                // channels per block
#define NCHUNK (CC / CCHUNK)     // 4 (atomic-accumulated, 4 writers/output)
#define CG 4                     // channels per phase (float4)
#define NG (CCHUNK / CG)         // 8 phases per block
#define NSPX (WW / TW)           // 5
#define NSPY (HH / HTILE)        // 6
#define NSP (NSPX * NSPY)        // 30 spatial tiles
#define NWG (NSP * BB * NCHUNK)  // 480 workgroups

#define FMA4S(a, t, s0, s1, s2, s3) \
    (a) = fmaf((s0), (t).x, fmaf((s1), (t).y, fmaf((s2), (t).z, fmaf((s3), (t).w, (a)))))

__global__ __launch_bounds__(256, 4)
void cost_volume_kernel(const float* __restrict__ src,
                        const float* __restrict__ tgt,
                        float* __restrict__ out) {
    __shared__ float4 tile[TILE_E];

    const int x   = threadIdx.x;          // 0..31
    const int hg  = threadIdx.y;          // 0..7 (row-pair group)
    const int tid = hg * TW + x;          // 0..255

    // chunk SLOWEST (flat stride 120 == 0 mod 8): all 4 chunk-writers of
    // any output land on one XCD = r0's counter-proven clean-atomic config.
    const int flat = blockIdx.x;          // 0..479
    const int ch   = flat / 120;
    const int rr_  = flat % 120;
    const int b    = rr_ / NSP;
    const int spl  = rr_ % NSP;
    const int wx   = spl % NSPX;
    const int wy   = spl / NSPX;

    const int c0 = ch * CCHUNK;
    const int w0 = wx * TW;
    const int h0 = wy * HTILE;

    const int w  = w0 + x;                // always < WW
    const int hb = h0 + hg * TH;          // thread's first pixel row

    const float* tgt_b = tgt + (size_t)(b * CC + c0) * HWSZ;
    const float* src_p = src + (size_t)(b * CC + c0) * HWSZ + hb * WW + w;

    // --- staging slots (invariant across phases): 960 elems, 4 slots ---
    int  sOff[4];
    bool sVal[4];
#pragma unroll
    for (int k = 0; k < 4; ++k) {
        const int idx = tid + k * 256;
        const int r   = idx / TCOLS;
        const int col = idx - r * TCOLS;
        const int gr  = h0 - RR + r;
        const int gc  = w0 - RR + col;
        sVal[k] = (idx < TILE_E) && gr >= 0 && gr < HH && gc >= 0 && gc < WW;
        sOff[k] = gr * WW + gc;
    }

    float4 pre[4];                        // tgt tile prefetch (4 f4/thread)
    float  sv[2][4];                      // src prefetch (2 rows x 4 channels)

    auto fetch = [&](int g) {
        const float* t = tgt_b + (size_t)(g * CG) * HWSZ;
#pragma unroll
        for (int k = 0; k < 4; ++k) {
            float4 v = make_float4(0.f, 0.f, 0.f, 0.f);
            if (sVal[k]) {
                const float* p = t + sOff[k];
                v.x = p[0];
                v.y = p[HWSZ];
                v.z = p[2 * HWSZ];
                v.w = p[3 * HWSZ];
            }
            pre[k] = v;
        }
        const float* s = src_p + (size_t)(g * CG) * HWSZ;
#pragma unroll
        for (int k = 0; k < 4; ++k) {
            sv[0][k] = s[k * HWSZ];
            sv[1][k] = s[k * HWSZ + WW];
        }
    };

    float acc0[NS], acc1[NS];
#pragma unroll
    for (int s = 0; s < NS; ++s) { acc0[s] = 0.f; acc1[s] = 0.f; }

    fetch(0);
    const int tr0 = RR + hg * TH;         // tile row of 1st pixel
    const int cc  = RR + x;               // tile col

    for (int g = 0; g < NG; ++g) {
        // store-early: staged regs -> LDS (4 b128 slots, last guarded)
        tile[tid]       = pre[0];
        tile[tid + 256] = pre[1];
        tile[tid + 512] = pre[2];
        if (tid < TILE_E - 768) tile[tid + 768] = pre[3];
        // snapshot src scalars before prefetch overwrites them
        const float a0 = sv[0][0], a1 = sv[0][1], a2 = sv[0][2], a3 = sv[0][3];
        const float b0 = sv[1][0], b1 = sv[1][1], b2 = sv[1][2], b3 = sv[1][3];
        __syncthreads();

        // depth-1 prefetch of next phase while computing this one
        if (g + 1 < NG) fetch(g + 1);

        // compute: 26 ds_read_b128 + 136 FMAs (2 pixels x 4 channels)
        // vertical chain: rows tr0-4 .. tr0+5 serve BOTH pixels
#pragma unroll
        for (int j = 0; j < 10; ++j) {
            float4 v = tile[(tr0 - RR + j) * TCOLS + cc];
            if (j <= 8) {                 // pixel 0 (row tr0): offsets -4..+4
                if (j == 4)      FMA4S(acc0[0],             v, a0, a1, a2, a3);
                else if (j < 4)  FMA4S(acc0[4 * (4 - j) - 3], v, a0, a1, a2, a3);
                else             FMA4S(acc0[4 * (j - 4) - 2], v, a0, a1, a2, a3);
            }
            if (j >= 1) {                 // pixel 1 (row tr0+1): offsets -4..+4
                if (j == 5)      FMA4S(acc1[0],             v, b0, b1, b2, b3);
                else if (j < 5)  FMA4S(acc1[4 * (5 - j) - 3], v, b0, b1, b2, b3);
                else             FMA4S(acc1[4 * (j - 5) - 2], v, b0, b1, b2, b3);
            }
        }
        // horizontal: per pixel row, offsets +-1..4
#pragma unroll
        for (int off = 1; off <= RR; ++off) {
            float4 l0 = tile[tr0 * TCOLS + cc - off];
            float4 r0 = tile[tr0 * TCOLS + cc + off];
            float4 l1 = tile[(tr0 + 1) * TCOLS + cc - off];
            float4 r1 = tile[(tr0 + 1) * TCOLS + cc + off];
            FMA4S(acc0[4 * off - 1], l0, a0, a1, a2, a3);
            FMA4S(acc0[4 * off    ], r0, a0, a1, a2, a3);
            FMA4S(acc1[4 * off - 1], l1, b0, b1, b2, b3);
            FMA4S(acc1[4 * off    ], r1, b0, b1, b2, b3);
        }
        __syncthreads();
    }

    // epilogue: atomic accumulate (4 same-XCD chunk-writers per output)
    float* op = out + (((size_t)b * NS) * HH + hb) * WW + w;
#pragma unroll
    for (int s = 0; s < NS; ++s) {
        atomicAdd(op + (size_t)s * HWSZ, acc0[s]);
        atomicAdd(op + (size_t)s * HWSZ + WW, acc1[s]);
    }
}

extern "C" void kernel_launch(void* const* d_in, const int* in_sizes, int n_in,
                              void* d_out, int out_size, void* d_ws, size_t ws_size,
                              hipStream_t stream) {
    const float* src = (const float*)d_in[0];
    const float* tgt = (const float*)d_in[1];
    float* out = (float*)d_out;

    // d_out is poisoned before every launch; we accumulate atomically -> zero it
    hipMemsetAsync(out, 0, (size_t)out_size * sizeof(float), stream);

    dim3 block(TW, 8, 1);      // 256 threads
    dim3 grid(NWG, 1, 1);      // 480 blocks
    cost_volume_kernel<<<grid, block, 0, stream>>>(src, tgt, out);
}

// Round 12
// 112.074 us; speedup vs baseline: 2.7032x; 2.7032x over previous
//
#include <hip/hip_runtime.h>

#define RR 4
#define NS 17
#define BB 4
#define CC 128
#define HH 96
#define WW 160
#define HWSZ (HH * WW)

// 512-thread block = two 256-thread channel-halves (r10-proven fusion), each
// half running the r1 skeleton with r9-proven CG=8 wide phases (two float4
// LDS buffers per half). CCHUNK=64 per block -> only TWO atomic writers per
// output (flat-stride 240 == 0 mod 8, r0's proven same-XCD config).
//
// SESSION LAWS (counter-proven over 12 rounds):
//  - SPILL LAW: compiler pins VGPR=64 under these bounds; any live set
//    over ~64 spills -> symmetric fetch/write HBM inflation (r2,r3,r7,
//    r8,r11). Per-half live here ~65 = r9's measured-clean envelope.
//    NEVER add register state beyond this (no depth-2, no TH=2).
//  - ATOMIC LAW: <=4 writers/output, same-XCD stride (r0); 8 writers
//    dirty regardless of placement (r5/r6). This kernel: 2 writers.
//  - r1 skeleton only: store-early, 2 barriers/phase, depth-1 prefetch
//    (write-late r2/r3 dirty).
//  - Occupancy is NOT binding (r10: 15->30 waves/CU ~ +1%).
// TRIPWIRES: WRITE_SIZE ~8,160 KB (>=30 MB -> revert to r10, final);
// VGPR 64-80 without symmetric inflation; FETCH 55-70 MB.
#define TW 32
#define HTILE 8
#define TROWS (HTILE + 2 * RR)   // 16
#define TCOLS (TW + 2 * RR)      // 40
#define TILE_E (TROWS * TCOLS)   // 640 float4 = 10240 B per buffer
#define CCHUNK 64                // channels per BLOCK -> 2 writers/output
#define NCHUNK (CC / CCHUNK)     // 2 (atomic-accumulated)
#define CHALF (CCHUNK / 2)       // 32 channels per half
#define CG 8                     // channels per phase (2x float4, r9-proven)
#define NGH (CHALF / CG)         // 4 phases per half
#define NSPX (WW / TW)           // 5
#define NSPY (HH / HTILE)        // 12
#define NSP (NSPX * NSPY)        // 60 spatial tiles
#define NWG (NSP * BB * NCHUNK)  // 480 workgroups

#define FMA4S(a, t, s0, s1, s2, s3) \
    (a) = fmaf((s0), (t).x, fmaf((s1), (t).y, fmaf((s2), (t).z, fmaf((s3), (t).w, (a)))))

__global__ __launch_bounds__(512, 4)
void cost_volume_kernel(const float* __restrict__ src,
                        const float* __restrict__ tgt,
                        float* __restrict__ out) {
    // [half][A/B buffer]: 4 x 10240 B = 40960 B
    __shared__ float4 tile[2][2][TILE_E];

    const int x    = threadIdx.x;         // 0..31
    const int yy   = threadIdx.y;         // 0..15
    const int half = yy >> 3;             // 0/1 channel half (wave-uniform)
    const int hg   = yy & 7;              // 0..7 pixel row group
    const int tid  = hg * TW + x;         // 0..255 within half

    // chunk SLOWEST: the 2 chunk-writers of any output are flat ids 240
    // apart (== 0 mod 8 -> same XCD slot, r0's clean-atomic config);
    // spatial tile fastest for L2 locality of halo re-reads.
    const int flat = blockIdx.x;          // 0..479
    const int ch64 = flat / 240;          // 0..1
    const int rem  = flat % 240;
    const int b    = rem / NSP;           // 0..3
    const int spl  = rem % NSP;           // 0..59
    const int wx   = spl % NSPX;
    const int wy   = spl / NSPX;

    const int c0 = ch64 * CCHUNK + half * CHALF;
    const int w0 = wx * TW;
    const int h0 = wy * HTILE;

    const int w = w0 + x;                 // always < WW
    const int h = h0 + hg;                // always < HH

    const float* tgt_b = tgt + (size_t)(b * CC + c0) * HWSZ;
    const float* src_p = src + (size_t)(b * CC + c0) * HWSZ + h * WW + w;

    // --- staging slots (invariant across phases) ---
    int  sOff[3];
    bool sVal[3];
#pragma unroll
    for (int k = 0; k < 3; ++k) {
        const int idx = tid + k * 256;
        const int r   = idx / TCOLS;
        const int col = idx - r * TCOLS;
        const int gr  = h0 - RR + r;
        const int gc  = w0 - RR + col;
        sVal[k] = (idx < TILE_E) && gr >= 0 && gr < HH && gc >= 0 && gc < WW;
        sOff[k] = gr * WW + gc;
    }

    float4 prA[3], prB[3];                // tgt prefetch (6 f4/thread)
    float  sv8[8];                        // src prefetch (8 channels)

    auto fetch = [&](int g) {
        const float* t = tgt_b + (size_t)(g * CG) * HWSZ;
#pragma unroll
        for (int k = 0; k < 3; ++k) {
            float4 va = make_float4(0.f, 0.f, 0.f, 0.f);
            float4 vb = make_float4(0.f, 0.f, 0.f, 0.f);
            if (sVal[k]) {
                const float* p = t + sOff[k];
                va.x = p[0];
                va.y = p[HWSZ];
                va.z = p[2 * HWSZ];
                va.w = p[3 * HWSZ];
                vb.x = p[4 * HWSZ];
                vb.y = p[5 * HWSZ];
                vb.z = p[6 * HWSZ];
                vb.w = p[7 * HWSZ];
            }
            prA[k] = va;
            prB[k] = vb;
        }
        const float* s = src_p + (size_t)(g * CG) * HWSZ;
#pragma unroll
        for (int k = 0; k < 8; ++k) sv8[k] = s[k * HWSZ];
    };

    float acc[NS];
#pragma unroll
    for (int s = 0; s < NS; ++s) acc[s] = 0.f;

    fetch(0);
    const int base = (RR + hg) * TCOLS + (RR + x);
    float4* tA = tile[half][0];
    float4* tB = tile[half][1];

    for (int g = 0; g < NGH; ++g) {
        // store-early: staged regs -> this half's two LDS buffers
        tA[tid]       = prA[0];
        tA[tid + 256] = prA[1];
        if (tid + 512 < TILE_E) tA[tid + 512] = prA[2];
        tB[tid]       = prB[0];
        tB[tid + 256] = prB[1];
        if (tid + 512 < TILE_E) tB[tid + 512] = prB[2];
        // snapshot src scalars before prefetch overwrites them
        const float a0 = sv8[0], a1 = sv8[1], a2 = sv8[2], a3 = sv8[3];
        const float b0 = sv8[4], b1 = sv8[5], b2 = sv8[6], b3 = sv8[7];
        __syncthreads();

        // depth-1 prefetch of next phase while computing this one
        if (g + 1 < NGH) fetch(g + 1);

        // compute: 34 ds_read_b128 + 272 FMAs (8 channels per phase)
        {
            float4 tc = tA[base];
            FMA4S(acc[0], tc, a0, a1, a2, a3);
#pragma unroll
            for (int off = 1; off <= RR; ++off) {
                float4 tu = tA[base - off * TCOLS];
                float4 td = tA[base + off * TCOLS];
                float4 tl = tA[base - off];
                float4 tr = tA[base + off];
                FMA4S(acc[4 * off - 3], tu, a0, a1, a2, a3);
                FMA4S(acc[4 * off - 2], td, a0, a1, a2, a3);
                FMA4S(acc[4 * off - 1], tl, a0, a1, a2, a3);
                FMA4S(acc[4 * off    ], tr, a0, a1, a2, a3);
            }
            float4 uc = tB[base];
            FMA4S(acc[0], uc, b0, b1, b2, b3);
#pragma unroll
            for (int off = 1; off <= RR; ++off) {
                float4 tu = tB[base - off * TCOLS];
                float4 td = tB[base + off * TCOLS];
                float4 tl = tB[base - off];
                float4 tr = tB[base + off];
                FMA4S(acc[4 * off - 3], tu, b0, b1, b2, b3);
                FMA4S(acc[4 * off - 2], td, b0, b1, b2, b3);
                FMA4S(acc[4 * off - 1], tl, b0, b1, b2, b3);
                FMA4S(acc[4 * off    ], tr, b0, b1, b2, b3);
            }
        }
        __syncthreads();
    }

    // --- combine halves in LDS, then 2-writer atomic epilogue ---
    // (final loop barrier ordered all tile reads before this reuse)
    // stride NS=17 odd -> bijective mod 32 banks; 4352 floats << 10240 f4.
    float* red = (float*)tile;
    if (half) {
#pragma unroll
        for (int s = 0; s < NS; ++s) red[tid * NS + s] = acc[s];
    }
    __syncthreads();
    if (!half) {
        float* op = out + (((size_t)b * NS) * HH + h) * WW + w;
#pragma unroll
        for (int s = 0; s < NS; ++s) {
            atomicAdd(op + (size_t)s * HWSZ, acc[s] + red[tid * NS + s]);
        }
    }
}

extern "C" void kernel_launch(void* const* d_in, const int* in_sizes, int n_in,
                              void* d_out, int out_size, void* d_ws, size_t ws_size,
                              hipStream_t stream) {
    const float* src = (const float*)d_in[0];
    const float* tgt = (const float*)d_in[1];
    float* out = (float*)d_out;

    // d_out is poisoned before every launch; we accumulate atomically -> zero it
    hipMemsetAsync(out, 0, (size_t)out_size * sizeof(float), stream);

    dim3 block(TW, 16, 1);     // 512 threads = two 256-halves
    dim3 grid(NWG, 1, 1);      // 480 blocks
    cost_volume_kernel<<<grid, block, 0, stream>>>(src, tgt, out);
}

// Round 13
// 111.369 us; speedup vs baseline: 2.7203x; 1.0063x over previous
//
#include <hip/hip_runtime.h>

#define RR 4
#define NS 17
#define BB 4
#define CC 128
#define HH 96
#define WW 160
#define HWSZ (HH * WW)

// 512 threads, ONE pixel per thread, 16x32 pixel tile (24x40 halo tile).
// r1/r10-proven phase skeleton (store-early, 2 barriers/phase, depth-1
// prefetch, CG=4). vs r10: halo amortized over 16 rows -> staged f4/px
// 2.5 -> 1.875 (-25% tgt gather + LDS writes + tgt fetch), and live set
// SHRINKS (pre[2] vs pre[3], ~50 regs < 64 wall).
//
// SESSION LAWS (counter-proven over 13 rounds):
//  - SPILL LAW: live set must stay under ~64 VGPR or scratch traffic
//    explodes (r2,r3,r7,r8,r11). Here ~50. Tripwire: sym fetch/write.
//  - ATOMIC LAW: <=4 writers/output on one XCD (r0: 4 B/atomic).
//    Here: 4 writers, chunk flat-stride 120 == 0 mod 8.
//  - r1 skeleton only (write-late r2/r3 dirty; depth-2 r8 dirty).
//  - Occupancy not binding at >=15 waves/CU (r10: 15->30 = +1%).
// DECISION RULE: bench >=105us -> r10 is final (structural plateau).
#define TW 32
#define HTILE 16
#define TROWS (HTILE + 2 * RR)   // 24
#define TCOLS (TW + 2 * RR)      // 40
#define TILE_E (TROWS * TCOLS)   // 960 float4 = 15360 B
#define CCHUNK 32                // channels per block -> 4 writers/output
#define NCHUNK (CC / CCHUNK)     // 4 (atomic-accumulated)
#define CG 4                     // channels per phase (float4)
#define NG (CCHUNK / CG)         // 8 phases per block
#define NSPX (WW / TW)           // 5
#define NSPY (HH / HTILE)        // 6
#define NSP (NSPX * NSPY)        // 30 spatial tiles
#define NWG (NSP * BB * NCHUNK)  // 480 workgroups

#define FMA4(a, t) \
    (a) = fmaf(svx, (t).x, fmaf(svy, (t).y, fmaf(svz, (t).z, fmaf(svw, (t).w, (a)))))

__global__ __launch_bounds__(512, 4)
void cost_volume_kernel(const float* __restrict__ src,
                        const float* __restrict__ tgt,
                        float* __restrict__ out) {
    __shared__ float4 tile[TILE_E];       // 15360 B

    const int x   = threadIdx.x;          // 0..31
    const int hg  = threadIdx.y;          // 0..15 pixel row in tile
    const int tid = hg * TW + x;          // 0..511

    // chunk SLOWEST (flat stride 120 == 0 mod 8): all 4 chunk-writers of
    // any output on one XCD = r0's counter-proven clean-atomic config;
    // spatial tile fastest within an XCD's range for L2 halo locality.
    const int flat = blockIdx.x;          // 0..479
    const int ch   = flat / 120;          // 0..3
    const int rem  = flat % 120;
    const int b    = rem / NSP;           // 0..3
    const int spl  = rem % NSP;           // 0..29
    const int wx   = spl % NSPX;
    const int wy   = spl / NSPX;

    const int c0 = ch * CCHUNK;
    const int w0 = wx * TW;
    const int h0 = wy * HTILE;

    const int w = w0 + x;                 // always < WW
    const int h = h0 + hg;                // always < HH

    const float* tgt_b = tgt + (size_t)(b * CC + c0) * HWSZ;
    const float* src_p = src + (size_t)(b * CC + c0) * HWSZ + h * WW + w;

    // --- staging slots (invariant across phases): 960 elems, 2 slots ---
    int  sOff[2];
    bool sVal[2];
#pragma unroll
    for (int k = 0; k < 2; ++k) {
        const int idx = tid + k * 512;
        const int r   = idx / TCOLS;
        const int col = idx - r * TCOLS;
        const int gr  = h0 - RR + r;
        const int gc  = w0 - RR + col;
        sVal[k] = (idx < TILE_E) && gr >= 0 && gr < HH && gc >= 0 && gc < WW;
        sOff[k] = gr * WW + gc;
    }

    float4 pre[2];                        // tgt tile prefetch (2 f4/thread)
    float  sv4[4];                        // src prefetch (4 channels)

    auto fetch = [&](int g) {
        const float* t = tgt_b + (size_t)(g * CG) * HWSZ;
#pragma unroll
        for (int k = 0; k < 2; ++k) {
            float4 v = make_float4(0.f, 0.f, 0.f, 0.f);
            if (sVal[k]) {
                const float* p = t + sOff[k];
                v.x = p[0];
                v.y = p[HWSZ];
                v.z = p[2 * HWSZ];
                v.w = p[3 * HWSZ];
            }
            pre[k] = v;
        }
        const float* s = src_p + (size_t)(g * CG) * HWSZ;
#pragma unroll
        for (int k = 0; k < 4; ++k) sv4[k] = s[k * HWSZ];
    };

    float acc[NS];
#pragma unroll
    for (int s = 0; s < NS; ++s) acc[s] = 0.f;

    fetch(0);
    const int base = (RR + hg) * TCOLS + (RR + x);

    for (int g = 0; g < NG; ++g) {
        // store-early: staged regs -> LDS (2 b128 slots, 2nd guarded)
        tile[tid] = pre[0];
        if (tid < TILE_E - 512) tile[tid + 512] = pre[1];
        // snapshot src scalars before prefetch overwrites them
        const float svx = sv4[0], svy = sv4[1], svz = sv4[2], svw = sv4[3];
        __syncthreads();

        // depth-1 prefetch of next phase while computing this one
        if (g + 1 < NG) fetch(g + 1);

        // compute: 17 ds_read_b128 + 68 FMAs (4 channels at once)
        {
            float4 tc = tile[base];
            FMA4(acc[0], tc);
#pragma unroll
            for (int off = 1; off <= RR; ++off) {
                float4 tu = tile[base - off * TCOLS];
                float4 td = tile[base + off * TCOLS];
                float4 tl = tile[base - off];
                float4 tr = tile[base + off];
                FMA4(acc[4 * off - 3], tu);
                FMA4(acc[4 * off - 2], td);
                FMA4(acc[4 * off - 1], tl);
                FMA4(acc[4 * off    ], tr);
            }
        }
        __syncthreads();
    }

    // epilogue: atomic accumulate (4 same-XCD chunk-writers per output)
    float* op = out + (((size_t)b * NS) * HH + h) * WW + w;
#pragma unroll
    for (int s = 0; s < NS; ++s) {
        atomicAdd(op + (size_t)s * HWSZ, acc[s]);
    }
}

extern "C" void kernel_launch(void* const* d_in, const int* in_sizes, int n_in,
                              void* d_out, int out_size, void* d_ws, size_t ws_size,
                              hipStream_t stream) {
    const float* src = (const float*)d_in[0];
    const float* tgt = (const float*)d_in[1];
    float* out = (float*)d_out;

    // d_out is poisoned before every launch; we accumulate atomically -> zero it
    hipMemsetAsync(out, 0, (size_t)out_size * sizeof(float), stream);

    dim3 block(TW, HTILE, 1);  // 512 threads, 1 px/thread
    dim3 grid(NWG, 1, 1);      // 480 blocks
    cost_volume_kernel<<<grid, block, 0, stream>>>(src, tgt, out);
}

// Round 14
// 106.433 us; speedup vs baseline: 2.8465x; 1.0464x over previous
//
#include <hip/hip_runtime.h>

#define RR 4
#define NS 17
#define BB 4
#define CC 128
#define HH 96
#define WW 160
#define HWSZ (HH * WW)

// FINAL (r10, best measured: 105.1us bench, ~33us kernel).
// 512-thread block = two 256-thread channel-halves sharing one 32x8 pixel
// tile. Each half runs the r1-proven inner loop (store-early, 2 barriers/
// phase, depth-1 prefetch after first barrier) on its own 16 channels in its
// own LDS buffer; halves combine via LDS; half A does one 4-writer atomic pass.
//
// SESSION LAWS (counter-proven over 14 rounds):
//  - SPILL LAW: compiler pins VGPR=64 here; live set over ~64 spills ->
//    symmetric fetch/write HBM inflation (r2,r3,r7,r8,r11).
//  - ATOMIC LAW: <=4 writers/output, all on ONE XCD (r0: 4 B/atomic);
//    8 writers or XCD-spanning writers -> 15-40x write dirt (r5,r6,r8).
//  - r1 skeleton only: store-early, 2 barriers/phase, depth-1 prefetch.
//  - Occupancy not binding >=15 waves/CU (r1 vs r10); CG=8 (r9,r12),
//    taller tile (r13), TH=2 (r11), CCHUNK=64 (r12) all neutral-or-worse.
// PLATEAU: kernel ~= HBM + LDS + VALU summed (lockstep serializes pipes);
// all overlap attempts hit the spill or atomic wall. Structural floor.
#define TW 32
#define HTILE 8
#define TROWS (HTILE + 2 * RR)   // 16
#define TCOLS (TW + 2 * RR)      // 40
#define TILE_E (TROWS * TCOLS)   // 640 float4 = 10240 B per half-buffer
#define CCHUNK 32                // channels per BLOCK -> 4 writers/output
#define NCHUNK (CC / CCHUNK)     // 4 (atomic-accumulated)
#define CHALF (CCHUNK / 2)       // 16 channels per half
#define CG 4                     // channels per phase (float4)
#define NGH (CHALF / CG)         // 4 phases per half
#define NSPX (WW / TW)           // 5
#define NSPY (HH / HTILE)        // 12

#define FMA4(a, t) \
    (a) = fmaf(svx, (t).x, fmaf(svy, (t).y, fmaf(svz, (t).z, fmaf(svw, (t).w, (a)))))

__global__ __launch_bounds__(512, 4)
void cost_volume_kernel(const float* __restrict__ src,
                        const float* __restrict__ tgt,
                        float* __restrict__ out) {
    __shared__ float4 tile[2][TILE_E];    // one buffer per half: 20480 B

    const int x    = threadIdx.x;         // 0..31
    const int yy   = threadIdx.y;         // 0..15
    const int half = yy >> 3;             // 0/1 channel half (wave-uniform)
    const int hg   = yy & 7;              // 0..7 pixel row group
    const int tid  = hg * TW + x;         // 0..255 within half

    // XCD mapping (HW: xcd = flat dispatch id % 8):
    //   xcd -> (batch, image-half); i = flat>>3 -> 30 contiguous spatial
    //   tiles (fastest) x 4 chunks (slowest).
    //   => all 4 chunk-writers of an output: same xcd, 240 ids apart
    //      (r0's counter-proven clean-atomic configuration), and each
    //      XCD's fetch stream is spatially contiguous within one batch.
    const int flat = blockIdx.x;          // 0..959
    const int xcd  = flat & 7;
    const int i    = flat >> 3;           // 0..119
    const int b    = xcd & 3;
    const int sph  = xcd >> 2;            // 0..1: top/bottom image half
    const int spl  = i % 30;              // local spatial tile, fastest
    const int ch32 = i / 30;              // chunk 0..3, slowest
    const int wx   = spl % NSPX;
    const int wy   = sph * 6 + spl / NSPX;

    const int c0 = ch32 * CCHUNK + half * CHALF;
    const int w0 = wx * TW;
    const int h0 = wy * HTILE;

    const int w = w0 + x;                 // always < WW
    const int h = h0 + hg;                // always < HH

    const float* tgt_b = tgt + (size_t)(b * CC + c0) * HWSZ;
    const float* src_p = src + (size_t)(b * CC + c0) * HWSZ + h * WW + w;

    // --- precompute staging slots (invariant across phases) ---
    int  sOff[3];
    bool sVal[3];
#pragma unroll
    for (int k = 0; k < 3; ++k) {
        const int idx = tid + k * 256;
        const int r   = idx / TCOLS;
        const int col = idx - r * TCOLS;
        const int gr  = h0 - RR + r;
        const int gc  = w0 - RR + col;
        sVal[k] = (idx < TILE_E) && gr >= 0 && gr < HH && gc >= 0 && gc < WW;
        sOff[k] = gr * WW + gc;
    }

    float4 pre[3];                        // tgt tile prefetch (3 f4/thread)
    float  sv4[4];                        // src prefetch (4 channels)

    auto fetch = [&](int g) {
        const float* t = tgt_b + (size_t)(g * CG) * HWSZ;
#pragma unroll
        for (int k = 0; k < 3; ++k) {
            float4 v = make_float4(0.f, 0.f, 0.f, 0.f);
            if (sVal[k]) {
                const float* p = t + sOff[k];
                v.x = p[0];
                v.y = p[HWSZ];
                v.z = p[2 * HWSZ];
                v.w = p[3 * HWSZ];
            }
            pre[k] = v;
        }
        const float* s = src_p + (size_t)(g * CG) * HWSZ;
#pragma unroll
        for (int k = 0; k < 4; ++k) sv4[k] = s[k * HWSZ];
    };

    float acc[NS];
#pragma unroll
    for (int s = 0; s < NS; ++s) acc[s] = 0.f;

    fetch(0);
    const int base = (RR + hg) * TCOLS + (RR + x);
    float4* tb = tile[half];

    for (int g = 0; g < NGH; ++g) {
        // store-early: write staged regs to this half's LDS buffer
        tb[tid]       = pre[0];
        tb[tid + 256] = pre[1];
        if (tid + 512 < TILE_E) tb[tid + 512] = pre[2];
        const float svx = sv4[0], svy = sv4[1], svz = sv4[2], svw = sv4[3];
        __syncthreads();

        // depth-1 prefetch of next phase while computing this one
        if (g + 1 < NGH) fetch(g + 1);

        // compute: 17 ds_read_b128 + 68 FMAs (4 channels at once)
        {
            float4 tc = tb[base];
            FMA4(acc[0], tc);
#pragma unroll
            for (int off = 1; off <= RR; ++off) {
                float4 tu = tb[base - off * TCOLS];
                float4 td = tb[base + off * TCOLS];
                float4 tl = tb[base - off];
                float4 tr = tb[base + off];
                FMA4(acc[4 * off - 3], tu);
                FMA4(acc[4 * off - 2], td);
                FMA4(acc[4 * off - 1], tl);
                FMA4(acc[4 * off    ], tr);
            }
        }
        __syncthreads();
    }

    // --- combine halves in LDS, then 4-writer atomic epilogue ---
    // (last loop barrier ordered all tile reads before this reuse)
    // stride NS=17 odd -> bijective mod 32 banks, conflict-free;
    // 4352 floats fit in the 5120-float tile allocation.
    float* red = (float*)tile;
    if (half) {
#pragma unroll
        for (int s = 0; s < NS; ++s) red[tid * NS + s] = acc[s];
    }
    __syncthreads();
    if (!half) {
        float* op = out + (((size_t)b * NS) * HH + h) * WW + w;
#pragma unroll
        for (int s = 0; s < NS; ++s) {
            atomicAdd(op + (size_t)s * HWSZ, acc[s] + red[tid * NS + s]);
        }
    }
}

extern "C" void kernel_launch(void* const* d_in, const int* in_sizes, int n_in,
                              void* d_out, int out_size, void* d_ws, size_t ws_size,
                              hipStream_t stream) {
    const float* src = (const float*)d_in[0];
    const float* tgt = (const float*)d_in[1];
    float* out = (float*)d_out;

    // d_out is poisoned before every launch; we accumulate atomically -> zero it
    hipMemsetAsync(out, 0, (size_t)out_size * sizeof(float), stream);

    dim3 block(TW, 16, 1);                // 512 threads = two 256-halves
    dim3 grid(NSPX * NSPY * BB * NCHUNK, 1, 1);  // 960 blocks, 1D for mapping
    cost_volume_kernel<<<grid, block, 0, stream>>>(src, tgt, out);
}